// Round 9
// baseline (176.969 us; speedup 1.0000x reference)
//
#include <hip/hip_runtime.h>
#include <hip/hip_bf16.h>
#include <stdint.h>

// Problem constants: B=4, deep_C=256, shallow_C=64, H=W=64, N=4096, qk_C=16.
#define LOG2E 1.44269504088896340736f

typedef __bf16 bf16x8 __attribute__((ext_vector_type(8)));
typedef float  f32x16 __attribute__((ext_vector_type(16)));

__device__ __forceinline__ uint32_t pack_bf2(float a, float b) {
    __bf16 ba = (__bf16)a;  // RNE
    __bf16 bb = (__bf16)b;
    uint16_t ua = __builtin_bit_cast(uint16_t, ba);
    uint16_t ub = __builtin_bit_cast(uint16_t, bb);
    return (uint32_t)ua | ((uint32_t)ub << 16);
}

// ---------------- Fused prepass: qk (blocks 0..63) + vconv (64..2111) ----
// Vb unit (16 B = 8 keys x 1 chan): gid = (((b*8+ct)*256+kb)*2+h1)*32+c
//   holds deep[b][ct*32+c][kb*16+h1*8 .. +7] as bf16.
// Qb rows: [b][n][32 bf16] = [hi c0..15 | lo c0..15], q PRE-SCALED by LOG2E.
// Kb2 units: addr_u16 = b*131072 + (n>>5)*1024 + s*512 + (h1*32+(n&31))*8,
//   s=0 hi / 1 lo  (a wave reads 1 KB contiguous per frag pair).
__global__ void __launch_bounds__(256) prepass(
    const float* __restrict__ deep, const float* __restrict__ shallow,
    const float* __restrict__ Wq, const float* __restrict__ bq,
    const float* __restrict__ Wk, const float* __restrict__ bk,
    uint16_t* __restrict__ Vb, uint16_t* __restrict__ Qb,
    uint16_t* __restrict__ Kb2) {
    const int blk = blockIdx.x;
    if (blk < 64) {
        int gid = blk * 256 + threadIdx.x;  // 0..16383 = b*4096+n
        int b = gid >> 12;
        int n = gid & 4095;
        const float* sp = shallow + (size_t)b * 64 * 4096 + n;
        float q[16], k[16];
#pragma unroll
        for (int o = 0; o < 16; ++o) { q[o] = bq[o]; k[o] = bk[o]; }
#pragma unroll 4
        for (int c = 0; c < 64; ++c) {
            float s = sp[(size_t)c * 4096];
#pragma unroll
            for (int o = 0; o < 16; ++o) {
                q[o] = fmaf(Wq[o * 64 + c], s, q[o]);
                k[o] = fmaf(Wk[o * 64 + c], s, k[o]);
            }
        }
        uint16_t* qr = Qb + (size_t)gid * 32;
        float klo[16];
#pragma unroll
        for (int o = 0; o < 16; ++o) {
            float qs = q[o] * LOG2E;             // fold log2(e) into Q
            __bf16 qh = (__bf16)qs; float qhf = (float)qh;
            __bf16 ql = (__bf16)(qs - qhf);
            qr[o]      = __builtin_bit_cast(uint16_t, qh);
            qr[16 + o] = __builtin_bit_cast(uint16_t, ql);
            klo[o] = k[o] - (float)((__bf16)k[o]);
        }
        uint16_t* kbase = Kb2 + (size_t)b * 131072 + (size_t)(n >> 5) * 1024
                              + (size_t)(n & 31) * 8;
        *(uint4*)(kbase +   0) = make_uint4(pack_bf2(k[0], k[1]),   pack_bf2(k[2], k[3]),
                                            pack_bf2(k[4], k[5]),   pack_bf2(k[6], k[7]));
        *(uint4*)(kbase + 256) = make_uint4(pack_bf2(k[8], k[9]),   pack_bf2(k[10], k[11]),
                                            pack_bf2(k[12], k[13]), pack_bf2(k[14], k[15]));
        *(uint4*)(kbase + 512) = make_uint4(pack_bf2(klo[0], klo[1]),   pack_bf2(klo[2], klo[3]),
                                            pack_bf2(klo[4], klo[5]),   pack_bf2(klo[6], klo[7]));
        *(uint4*)(kbase + 768) = make_uint4(pack_bf2(klo[8], klo[9]),   pack_bf2(klo[10], klo[11]),
                                            pack_bf2(klo[12], klo[13]), pack_bf2(klo[14], klo[15]));
    } else {
        int gid = (blk - 64) * 256 + threadIdx.x;   // 0..524287
        int c  = gid & 31;
        int h1 = (gid >> 5) & 1;
        int kb = (gid >> 6) & 255;
        int ct = (gid >> 14) & 7;
        int b  = gid >> 17;
        int chan = ct * 32 + c;
        int key  = kb * 16 + h1 * 8;
        const float4* dp = (const float4*)(deep + ((size_t)(b * 256 + chan) * 4096 + key));
        float4 f0 = dp[0], f1 = dp[1];
        ((uint4*)Vb)[gid] = make_uint4(pack_bf2(f0.x, f0.y), pack_bf2(f0.z, f0.w),
                                       pack_bf2(f1.x, f1.y), pack_bf2(f1.z, f1.w));
    }
}

// ---------------- Main fused flash-attention kernel ----------------------
// Grid: 256 blocks x 512 threads (8 waves, 2/SIMD). Block = (b, 64-query
// tile), all 256 chans. Homogeneous waves (r4 base, the best structure):
// wave w computes QK^T+softmax for key-slice w of ss+1 AND PV for chan-tile
// w of ss. KEY CHANGE vs r4: barriers are raw s_barrier with lgkmcnt(0)
// only — global loads (V ping-pong, K prefetch) stay IN FLIGHT across the
// barrier (T4 counted-vmcnt discipline via compiler dependency waits),
// killing the per-ss vmcnt(0) drain + post-barrier convoy that all prior
// rounds paid (~6k stall cy/ss). V is ping-ponged a full superstep ahead.
__global__ void __launch_bounds__(512, 2) attn_main(
    const uint16_t* __restrict__ Qb, const uint16_t* __restrict__ Kb2,
    const uint16_t* __restrict__ Vb, const float* __restrict__ deep,
    const float* __restrict__ gamma, float* __restrict__ out) {
    const int lane = threadIdx.x & 63;
    const int w    = threadIdx.x >> 6;   // 0..7: key-slice (produce) / ch-tile (PV)
    const int col  = lane & 31;
    const int h1   = lane >> 5;

    // XCD-locality: one batch per XCD pair (V slice 2 MB < 4 MB L2/XCD).
    const int bid = blockIdx.x;
    const int xcd = bid & 7;
    const int b   = xcd >> 1;
    const int qt  = ((bid >> 3) << 1) + (xcd & 1);   // 0..63
    const int n0q = qt * 64;

    __shared__ uint4 Pl[2][2][16][2][32];  // par, qh, frag, h1', col  = 64 KB
    __shared__ float Ls[2][2][16][32];     // par, qh, w*2+h1, col     =  8 KB

    // Hoisted Q B-frags (pre-scaled by LOG2E)
    uint4 ubqh[2], ubql[2];
#pragma unroll
    for (int qh = 0; qh < 2; ++qh) {
        const uint16_t* qrow = Qb + ((size_t)(b * 4096 + n0q + qh * 32 + col)) * 32;
        ubqh[qh] = *(const uint4*)(qrow + h1 * 8);
        ubql[qh] = *(const uint4*)(qrow + 16 + h1 * 8);
    }
    const uint16_t* kbase = Kb2 + (size_t)b * 131072 + (size_t)w * 1024
                                + (size_t)lane * 8;                  // + ss*8192
    const uint16_t* vlane = Vb + (size_t)(b * 8 + w) * 131072
                               + (size_t)h1 * 256 + (size_t)col * 8; // + (ss*16+f)*512

    f32x16 acc0 = {0,0,0,0,0,0,0,0,0,0,0,0,0,0,0,0};
    f32x16 acc1 = {0,0,0,0,0,0,0,0,0,0,0,0,0,0,0,0};
    float l0 = 0.0f, l1 = 0.0f;
    uint4 vA[16], vB[16];                  // V ping-pong (full superstep each)
    uint4 ukh, ukl;                        // K frags for next produce

    // produce P(s) -> Pl[s&1]; reloads ukh/ukl = K(s+1) after last use.
    auto produce = [&](int s) {
        const int pr = s & 1;
        bf16x8 akh = __builtin_bit_cast(bf16x8, ukh);
        bf16x8 akl = __builtin_bit_cast(bf16x8, ukl);
#pragma unroll
        for (int qh = 0; qh < 2; ++qh) {
            bf16x8 bh = __builtin_bit_cast(bf16x8, ubqh[qh]);
            bf16x8 bl = __builtin_bit_cast(bf16x8, ubql[qh]);
            f32x16 e = {0,0,0,0,0,0,0,0,0,0,0,0,0,0,0,0};
            e = __builtin_amdgcn_mfma_f32_32x32x16_bf16(akh, bh, e, 0, 0, 0);
            e = __builtin_amdgcn_mfma_f32_32x32x16_bf16(akl, bh, e, 0, 0, 0);
            e = __builtin_amdgcn_mfma_f32_32x32x16_bf16(akh, bl, e, 0, 0, 0);
            if (qh == 1) {                 // K(s+1) reload after last akh/akl use
                const int sn = (s < 15) ? s + 1 : s;
                ukh = *(const uint4*)(kbase + (size_t)sn * 8192);
                ukl = *(const uint4*)(kbase + (size_t)sn * 8192 + 512);
            }
            float p[16];
#pragma unroll
            for (int r = 0; r < 16; ++r) p[r] = exp2f(e[r]);   // Q pre-scaled
            float t0 = (p[0] + p[1]) + (p[2] + p[3]);
            float t1 = (p[4] + p[5]) + (p[6] + p[7]);
            float t2 = (p[8] + p[9]) + (p[10] + p[11]);
            float t3 = (p[12] + p[13]) + (p[14] + p[15]);
            Ls[pr][qh][w * 2 + h1][col] = (t0 + t1) + (t2 + t3);
            uint32_t pk0 = pack_bf2(p[0],  p[1]),  pk1 = pack_bf2(p[2],  p[3]);
            uint32_t pk2 = pack_bf2(p[4],  p[5]),  pk3 = pack_bf2(p[6],  p[7]);
            uint32_t pk4 = pack_bf2(p[8],  p[9]),  pk5 = pack_bf2(p[10], p[11]);
            uint32_t pk6 = pack_bf2(p[12], p[13]), pk7 = pack_bf2(p[14], p[15]);
            ((uint2*)&Pl[pr][qh][2 * w    ][0][col])[h1] = make_uint2(pk0, pk1);
            ((uint2*)&Pl[pr][qh][2 * w    ][1][col])[h1] = make_uint2(pk2, pk3);
            ((uint2*)&Pl[pr][qh][2 * w + 1][0][col])[h1] = make_uint2(pk4, pk5);
            ((uint2*)&Pl[pr][qh][2 * w + 1][1][col])[h1] = make_uint2(pk6, pk7);
        }
    };

// LDS-only barrier: Pl/Ls visibility without draining global loads.
#define LBAR()                                                      \
    {                                                               \
        asm volatile("s_waitcnt lgkmcnt(0)" ::: "memory");          \
        __builtin_amdgcn_s_barrier();                               \
    }
// Issue all 16 V frags of superstep ssn into buffer nxt (stays in flight).
#define VISS(nxt, ssn)                                              \
    {                                                               \
        const uint16_t* _vp = vlane + (size_t)(ssn) * 8192;         \
        _Pragma("unroll")                                           \
        for (int f = 0; f < 16; ++f)                                \
            nxt[f] = *(const uint4*)(_vp + f * 512);                \
    }
// One superstep body: V(ss+1)->NXT issue | produce(ss+1) | PV(ss) on CUR.
#define SSBODY(ss, CUR, NXT)                                        \
    {                                                               \
        const int par = (ss) & 1;                                   \
        if ((ss) < 15) VISS(NXT, (ss) + 1);                         \
        if ((ss) < 15) produce((ss) + 1);                           \
        __builtin_amdgcn_s_setprio(1);                              \
        _Pragma("unroll")                                           \
        for (int f = 0; f < 16; ++f) {                              \
            uint4 pb0 = Pl[par][0][f][h1][col];                     \
            uint4 pb1 = Pl[par][1][f][h1][col];                     \
            bf16x8 av = __builtin_bit_cast(bf16x8, CUR[f]);         \
            acc0 = __builtin_amdgcn_mfma_f32_32x32x16_bf16(         \
                av, __builtin_bit_cast(bf16x8, pb0), acc0, 0, 0, 0);\
            acc1 = __builtin_amdgcn_mfma_f32_32x32x16_bf16(         \
                av, __builtin_bit_cast(bf16x8, pb1), acc1, 0, 0, 0);\
        }                                                           \
        __builtin_amdgcn_s_setprio(0);                              \
        _Pragma("unroll")                                           \
        for (int j = 0; j < 16; ++j) {                              \
            l0 += Ls[par][0][j][col];                               \
            l1 += Ls[par][1][j][col];                               \
        }                                                           \
        LBAR();                                                     \
    }

    // ---- prologue ----
    VISS(vA, 0);                            // V(0) in flight
    ukh = *(const uint4*)(kbase);
    ukl = *(const uint4*)(kbase + 512);
    produce(0);                             // Pl[0]; leaves ukh=K(1)
    LBAR();                                 // barrier 0

    // ---- main loop: 16 supersteps, manual 2-unroll for ping-pong names ----
    for (int s2 = 0; s2 < 8; ++s2) {
        const int ssA = s2 * 2;
        SSBODY(ssA, vA, vB);                // even ss: consume vA, fill vB
        SSBODY(ssA + 1, vB, vA);            // odd  ss: consume vB, fill vA
    }

    // ---- epilogue: out = gamma * acc/l + deep ----
    const float g   = gamma[0];
    const float gr0 = g / l0;
    const float gr1 = g / l1;
#pragma unroll
    for (int r = 0; r < 16; ++r) {
        const int crow = (r & 3) + 8 * (r >> 2) + 4 * h1;
        const int chan = w * 32 + crow;
        size_t i0 = (size_t)(b * 256 + chan) * 4096 + n0q + col;
        out[i0] = fmaf(gr0, acc0[r], deep[i0]);
        size_t i1 = i0 + 32;
        out[i1] = fmaf(gr1, acc1[r], deep[i1]);
    }
#undef SSBODY
#undef VISS
#undef LBAR
}

extern "C" void kernel_launch(void* const* d_in, const int* in_sizes, int n_in,
                              void* d_out, int out_size, void* d_ws, size_t ws_size,
                              hipStream_t stream) {
    const float* deep    = (const float*)d_in[0];
    const float* shallow = (const float*)d_in[1];
    const float* Wq      = (const float*)d_in[2];
    const float* bq      = (const float*)d_in[3];
    const float* Wk      = (const float*)d_in[4];
    const float* bk      = (const float*)d_in[5];
    const float* gamma   = (const float*)d_in[6];
    float* out = (float*)d_out;

    // ws layout: Vb swizzled bf16 (8 MiB) | Qb (1 MiB) | Kb2 (1 MiB)
    uint16_t* Vb  = (uint16_t*)d_ws;
    uint16_t* Qb  = (uint16_t*)((char*)d_ws + (size_t)8 * 1024 * 1024);
    uint16_t* Kb2 = (uint16_t*)((char*)d_ws + (size_t)9 * 1024 * 1024);

    hipLaunchKernelGGL(prepass, dim3(2112), dim3(256), 0, stream,
                       deep, shallow, Wq, bq, Wk, bk, Vb, Qb, Kb2);
    hipLaunchKernelGGL(attn_main, dim3(256), dim3(512), 0, stream,
                       Qb, Kb2, Vb, deep, gamma, out);
}

// Round 11
// 102.313 us; speedup vs baseline: 1.7297x; 1.7297x over previous
//
#include <hip/hip_runtime.h>
#include <hip/hip_bf16.h>
#include <stdint.h>

// Problem constants: B=4, deep_C=256, shallow_C=64, H=W=64, N=4096, qk_C=16.
#define LOG2E 1.44269504088896340736f

typedef __bf16 bf16x8 __attribute__((ext_vector_type(8)));
typedef float  f32x16 __attribute__((ext_vector_type(16)));

__device__ __forceinline__ uint32_t pack_bf2(float a, float b) {
    __bf16 ba = (__bf16)a;  // RNE
    __bf16 bb = (__bf16)b;
    uint16_t ua = __builtin_bit_cast(uint16_t, ba);
    uint16_t ub = __builtin_bit_cast(uint16_t, bb);
    return (uint32_t)ua | ((uint32_t)ub << 16);
}

// ---------------- Fused prepass: qk (blocks 0..63) + vconv (64..2111) ----
// Vb unit (16 B = 8 keys x 1 chan): gid = (((b*8+ct)*256+kb)*2+h1)*32+c
//   holds deep[b][ct*32+c][kb*16+h1*8 .. +7] as bf16.
// Qb rows: [b][n][32 bf16] = [hi c0..15 | lo c0..15], q PRE-SCALED by LOG2E.
// Kb2 units: addr_u16 = b*131072 + (n>>5)*1024 + s*512 + (h1*32+(n&31))*8,
//   s=0 hi / 1 lo  (a wave reads 1 KB contiguous per frag pair).
__global__ void __launch_bounds__(256) prepass(
    const float* __restrict__ deep, const float* __restrict__ shallow,
    const float* __restrict__ Wq, const float* __restrict__ bq,
    const float* __restrict__ Wk, const float* __restrict__ bk,
    uint16_t* __restrict__ Vb, uint16_t* __restrict__ Qb,
    uint16_t* __restrict__ Kb2) {
    const int blk = blockIdx.x;
    if (blk < 64) {
        int gid = blk * 256 + threadIdx.x;  // 0..16383 = b*4096+n
        int b = gid >> 12;
        int n = gid & 4095;
        const float* sp = shallow + (size_t)b * 64 * 4096 + n;
        float q[16], k[16];
#pragma unroll
        for (int o = 0; o < 16; ++o) { q[o] = bq[o]; k[o] = bk[o]; }
#pragma unroll 4
        for (int c = 0; c < 64; ++c) {
            float s = sp[(size_t)c * 4096];
#pragma unroll
            for (int o = 0; o < 16; ++o) {
                q[o] = fmaf(Wq[o * 64 + c], s, q[o]);
                k[o] = fmaf(Wk[o * 64 + c], s, k[o]);
            }
        }
        uint16_t* qr = Qb + (size_t)gid * 32;
        float klo[16];
#pragma unroll
        for (int o = 0; o < 16; ++o) {
            float qs = q[o] * LOG2E;             // fold log2(e) into Q
            __bf16 qh = (__bf16)qs; float qhf = (float)qh;
            __bf16 ql = (__bf16)(qs - qhf);
            qr[o]      = __builtin_bit_cast(uint16_t, qh);
            qr[16 + o] = __builtin_bit_cast(uint16_t, ql);
            klo[o] = k[o] - (float)((__bf16)k[o]);
        }
        uint16_t* kbase = Kb2 + (size_t)b * 131072 + (size_t)(n >> 5) * 1024
                              + (size_t)(n & 31) * 8;
        *(uint4*)(kbase +   0) = make_uint4(pack_bf2(k[0], k[1]),   pack_bf2(k[2], k[3]),
                                            pack_bf2(k[4], k[5]),   pack_bf2(k[6], k[7]));
        *(uint4*)(kbase + 256) = make_uint4(pack_bf2(k[8], k[9]),   pack_bf2(k[10], k[11]),
                                            pack_bf2(k[12], k[13]), pack_bf2(k[14], k[15]));
        *(uint4*)(kbase + 512) = make_uint4(pack_bf2(klo[0], klo[1]),   pack_bf2(klo[2], klo[3]),
                                            pack_bf2(klo[4], klo[5]),   pack_bf2(klo[6], klo[7]));
        *(uint4*)(kbase + 768) = make_uint4(pack_bf2(klo[8], klo[9]),   pack_bf2(klo[10], klo[11]),
                                            pack_bf2(klo[12], klo[13]), pack_bf2(klo[14], klo[15]));
    } else {
        int gid = (blk - 64) * 256 + threadIdx.x;   // 0..524287
        int c  = gid & 31;
        int h1 = (gid >> 5) & 1;
        int kb = (gid >> 6) & 255;
        int ct = (gid >> 14) & 7;
        int b  = gid >> 17;
        int chan = ct * 32 + c;
        int key  = kb * 16 + h1 * 8;
        const float4* dp = (const float4*)(deep + ((size_t)(b * 256 + chan) * 4096 + key));
        float4 f0 = dp[0], f1 = dp[1];
        ((uint4*)Vb)[gid] = make_uint4(pack_bf2(f0.x, f0.y), pack_bf2(f0.z, f0.w),
                                       pack_bf2(f1.x, f1.y), pack_bf2(f1.z, f1.w));
    }
}

// ---------------- Main fused flash-attention kernel ----------------------
// Grid: 512 blocks x 512 threads (8 waves). Block = (b, 64-query tile,
// 128-CHANNEL HALF) -> 2 blocks/CU co-resident (LDS 72 KB x 2 = 144 <= 160,
// VGPR capped at 128 via __launch_bounds__(512,4)) = 4 waves/SIMD, doubling
// latency-hiding vs every prior round (measured wall was stall, not pipe).
// Homogeneous waves: wave w produces QK+softmax for key-slice w of ss+1
// (both qh — duplicated across the two channel-half blocks, cheap) AND does
// PV for (chan-tile w&3, qh w>>2) of ss. Numerics: exp2f + pack_bf2 ONLY
// (r10's inline-asm v_exp_f32 hit the uncovered trans->VALU hazard: the
// hazard recognizer can't see inside asm blobs -> stale reads, absmax 4.25).
// Barriers are lgkmcnt-only (LBAR): K prefetch stays in flight across them.
__global__ void __launch_bounds__(512, 4) attn_main(
    const uint16_t* __restrict__ Qb, const uint16_t* __restrict__ Kb2,
    const uint16_t* __restrict__ Vb, const float* __restrict__ deep,
    const float* __restrict__ gamma, float* __restrict__ out) {
    const int lane = threadIdx.x & 63;
    const int w    = threadIdx.x >> 6;   // 0..7
    const int col  = lane & 31;
    const int h1   = lane >> 5;
    const int qhc  = w >> 2;             // PV query-half of this wave
    const int ct_l = w & 3;              // PV chan-tile within the half

    // XCD-locality: xcd = bid&7; XCD pair per b; chan-half tied to XCD so
    // each XCD streams a 1 MB V half-slice (L2-resident).
    const int bid = blockIdx.x;          // 0..511
    const int xcd = bid & 7;
    const int b   = xcd >> 1;
    const int ch  = xcd & 1;             // channel half (0:0-127, 1:128-255)
    const int qt  = bid >> 3;            // 0..63
    const int n0q = qt * 64;

    __shared__ uint4 Pl[2][2][16][2][32];  // par, qh, frag, h1', col  = 64 KB
    __shared__ float Ls[2][2][16][32];     // par, qh, w*2+h1, col     =  8 KB

    // Hoisted Q B-frags, both query halves (produce needs both)
    uint4 ubqh[2], ubql[2];
#pragma unroll
    for (int qh = 0; qh < 2; ++qh) {
        const uint16_t* qrow = Qb + ((size_t)(b * 4096 + n0q + qh * 32 + col)) * 32;
        ubqh[qh] = *(const uint4*)(qrow + h1 * 8);
        ubql[qh] = *(const uint4*)(qrow + 16 + h1 * 8);
    }
    const uint16_t* kbase = Kb2 + (size_t)b * 131072 + (size_t)w * 1024
                                + (size_t)lane * 8;                  // + ss*8192
    const int ct = ch * 4 + ct_l;        // global chan-tile 0..7
    const uint16_t* vlane = Vb + (size_t)(b * 8 + ct) * 131072
                               + (size_t)h1 * 256 + (size_t)col * 8; // + (ss*16+f)*512

    f32x16 acc = {0,0,0,0,0,0,0,0,0,0,0,0,0,0,0,0};
    float l = 0.0f;
    uint4 ukh, ukl;                      // K frags for next produce

    // produce P(s) -> Pl[s&1] (both qh); reloads ukh/ukl = K(s+1) after use.
    auto produce = [&](int s) {
        const int pr = s & 1;
        bf16x8 akh = __builtin_bit_cast(bf16x8, ukh);
        bf16x8 akl = __builtin_bit_cast(bf16x8, ukl);
#pragma unroll
        for (int qh = 0; qh < 2; ++qh) {
            bf16x8 bh = __builtin_bit_cast(bf16x8, ubqh[qh]);
            bf16x8 bl = __builtin_bit_cast(bf16x8, ubql[qh]);
            f32x16 e = {0,0,0,0,0,0,0,0,0,0,0,0,0,0,0,0};
            e = __builtin_amdgcn_mfma_f32_32x32x16_bf16(akh, bh, e, 0, 0, 0);
            e = __builtin_amdgcn_mfma_f32_32x32x16_bf16(akl, bh, e, 0, 0, 0);
            e = __builtin_amdgcn_mfma_f32_32x32x16_bf16(akh, bl, e, 0, 0, 0);
            if (qh == 1) {               // K(s+1) reload after last akh/akl use
                const int sn = (s < 15) ? s + 1 : s;
                ukh = *(const uint4*)(kbase + (size_t)sn * 8192);
                ukl = *(const uint4*)(kbase + (size_t)sn * 8192 + 512);
            }
            float p[16];
#pragma unroll
            for (int r = 0; r < 16; ++r) p[r] = exp2f(e[r]);   // Q pre-scaled
            float t0 = (p[0] + p[1]) + (p[2] + p[3]);
            float t1 = (p[4] + p[5]) + (p[6] + p[7]);
            float t2 = (p[8] + p[9]) + (p[10] + p[11]);
            float t3 = (p[12] + p[13]) + (p[14] + p[15]);
            Ls[pr][qh][w * 2 + h1][col] = (t0 + t1) + (t2 + t3);
            uint32_t pk0 = pack_bf2(p[0],  p[1]),  pk1 = pack_bf2(p[2],  p[3]);
            uint32_t pk2 = pack_bf2(p[4],  p[5]),  pk3 = pack_bf2(p[6],  p[7]);
            uint32_t pk4 = pack_bf2(p[8],  p[9]),  pk5 = pack_bf2(p[10], p[11]);
            uint32_t pk6 = pack_bf2(p[12], p[13]), pk7 = pack_bf2(p[14], p[15]);
            ((uint2*)&Pl[pr][qh][2 * w    ][0][col])[h1] = make_uint2(pk0, pk1);
            ((uint2*)&Pl[pr][qh][2 * w    ][1][col])[h1] = make_uint2(pk2, pk3);
            ((uint2*)&Pl[pr][qh][2 * w + 1][0][col])[h1] = make_uint2(pk4, pk5);
            ((uint2*)&Pl[pr][qh][2 * w + 1][1][col])[h1] = make_uint2(pk6, pk7);
        }
    };

// LDS-only barrier: Pl/Ls visibility without draining global loads (vmcnt
// stays counted — K prefetch rides across; V is consumed within the body).
#define LBAR()                                                      \
    {                                                               \
        asm volatile("s_waitcnt lgkmcnt(0)" ::: "memory");          \
        __builtin_amdgcn_s_barrier();                               \
    }

    // ---- prologue ----
    ukh = *(const uint4*)(kbase);
    ukl = *(const uint4*)(kbase + 512);
    produce(0);                             // Pl[0]; leaves ukh=K(1)
    LBAR();                                 // barrier 0

    // ---- main loop: one LDS-barrier per superstep ----
    for (int ss = 0; ss < 16; ++ss) {
        const int par = ss & 1;
        const uint16_t* vss = vlane + (size_t)ss * 8192;
        uint4 vr[8];
        // half 0 issue (latency covered by produce below)
#pragma unroll
        for (int f = 0; f < 8; ++f) vr[f] = *(const uint4*)(vss + f * 512);
        if (ss < 15) produce(ss + 1);       // writes Pl[par^1]
        __builtin_amdgcn_s_setprio(1);
#pragma unroll
        for (int f = 0; f < 8; ++f) {
            uint4 pb = Pl[par][qhc][f][h1][col];
            acc = __builtin_amdgcn_mfma_f32_32x32x16_bf16(
                __builtin_bit_cast(bf16x8, vr[f]),
                __builtin_bit_cast(bf16x8, pb), acc, 0, 0, 0);
        }
        __builtin_amdgcn_s_setprio(0);
        // half 1 (WAR on vr safe: in-order issue, MFMAs above already read)
#pragma unroll
        for (int f = 0; f < 8; ++f) vr[f] = *(const uint4*)(vss + (8 + f) * 512);
        __builtin_amdgcn_s_setprio(1);
#pragma unroll
        for (int f = 0; f < 8; ++f) {
            uint4 pb = Pl[par][qhc][8 + f][h1][col];
            acc = __builtin_amdgcn_mfma_f32_32x32x16_bf16(
                __builtin_bit_cast(bf16x8, vr[f]),
                __builtin_bit_cast(bf16x8, pb), acc, 0, 0, 0);
        }
        __builtin_amdgcn_s_setprio(0);
#pragma unroll
        for (int j = 0; j < 16; ++j) l += Ls[par][qhc][j][col];
        LBAR();                             // barriers 1..16
    }

    // ---- epilogue: out = gamma * acc/l + deep ----
    const float g  = gamma[0];
    const float gr = g / l;
#pragma unroll
    for (int r = 0; r < 16; ++r) {
        const int crow = (r & 3) + 8 * (r >> 2) + 4 * h1;
        const int chan = ct * 32 + crow;
        size_t i0 = (size_t)(b * 256 + chan) * 4096 + n0q + qhc * 32 + col;
        out[i0] = fmaf(gr, acc[r], deep[i0]);
    }
#undef LBAR
}

extern "C" void kernel_launch(void* const* d_in, const int* in_sizes, int n_in,
                              void* d_out, int out_size, void* d_ws, size_t ws_size,
                              hipStream_t stream) {
    const float* deep    = (const float*)d_in[0];
    const float* shallow = (const float*)d_in[1];
    const float* Wq      = (const float*)d_in[2];
    const float* bq      = (const float*)d_in[3];
    const float* Wk      = (const float*)d_in[4];
    const float* bk      = (const float*)d_in[5];
    const float* gamma   = (const float*)d_in[6];
    float* out = (float*)d_out;

    // ws layout: Vb swizzled bf16 (8 MiB) | Qb (1 MiB) | Kb2 (1 MiB)
    uint16_t* Vb  = (uint16_t*)d_ws;
    uint16_t* Qb  = (uint16_t*)((char*)d_ws + (size_t)8 * 1024 * 1024);
    uint16_t* Kb2 = (uint16_t*)((char*)d_ws + (size_t)9 * 1024 * 1024);

    hipLaunchKernelGGL(prepass, dim3(2112), dim3(256), 0, stream,
                       deep, shallow, Wq, bq, Wk, bk, Vb, Qb, Kb2);
    hipLaunchKernelGGL(attn_main, dim3(512), dim3(512), 0, stream,
                       Qb, Kb2, Vb, deep, gamma, out);
}

// Round 12
// 80.374 us; speedup vs baseline: 2.2018x; 1.2730x over previous
//
#include <hip/hip_runtime.h>
#include <hip/hip_bf16.h>
#include <stdint.h>

// Problem constants: B=4, deep_C=256, shallow_C=64, H=W=64, N=4096, qk_C=16.
#define LOG2E 1.44269504088896340736f

typedef __bf16 bf16x8 __attribute__((ext_vector_type(8)));
typedef float  f32x16 __attribute__((ext_vector_type(16)));

__device__ __forceinline__ uint32_t pack_bf2(float a, float b) {
    __bf16 ba = (__bf16)a;  // RNE
    __bf16 bb = (__bf16)b;
    uint16_t ua = __builtin_bit_cast(uint16_t, ba);
    uint16_t ub = __builtin_bit_cast(uint16_t, bb);
    return (uint32_t)ua | ((uint32_t)ub << 16);
}

// ---------------- Fused prepass: qk (blocks 0..63) + vconv (64..2111) ----
// Vb unit (16 B = 8 keys x 1 chan): gid = (((b*8+ct)*256+kb)*2+h1)*32+c
//   holds deep[b][ct*32+c][kb*16+h1*8 .. +7] as bf16.
// Qb rows: [b][n][32 bf16] = [hi c0..15 | lo c0..15], q PRE-SCALED by LOG2E.
// Kb2 units: addr_u16 = b*131072 + (n>>5)*1024 + s*512 + (h1*32+(n&31))*8,
//   s=0 hi / 1 lo  (a wave reads 1 KB contiguous per frag pair).
__global__ void __launch_bounds__(256) prepass(
    const float* __restrict__ deep, const float* __restrict__ shallow,
    const float* __restrict__ Wq, const float* __restrict__ bq,
    const float* __restrict__ Wk, const float* __restrict__ bk,
    uint16_t* __restrict__ Vb, uint16_t* __restrict__ Qb,
    uint16_t* __restrict__ Kb2) {
    const int blk = blockIdx.x;
    if (blk < 64) {
        int gid = blk * 256 + threadIdx.x;  // 0..16383 = b*4096+n
        int b = gid >> 12;
        int n = gid & 4095;
        const float* sp = shallow + (size_t)b * 64 * 4096 + n;
        float q[16], k[16];
#pragma unroll
        for (int o = 0; o < 16; ++o) { q[o] = bq[o]; k[o] = bk[o]; }
#pragma unroll 4
        for (int c = 0; c < 64; ++c) {
            float s = sp[(size_t)c * 4096];
#pragma unroll
            for (int o = 0; o < 16; ++o) {
                q[o] = fmaf(Wq[o * 64 + c], s, q[o]);
                k[o] = fmaf(Wk[o * 64 + c], s, k[o]);
            }
        }
        uint16_t* qr = Qb + (size_t)gid * 32;
        float klo[16];
#pragma unroll
        for (int o = 0; o < 16; ++o) {
            float qs = q[o] * LOG2E;             // fold log2(e) into Q
            __bf16 qh = (__bf16)qs; float qhf = (float)qh;
            __bf16 ql = (__bf16)(qs - qhf);
            qr[o]      = __builtin_bit_cast(uint16_t, qh);
            qr[16 + o] = __builtin_bit_cast(uint16_t, ql);
            klo[o] = k[o] - (float)((__bf16)k[o]);
        }
        uint16_t* kbase = Kb2 + (size_t)b * 131072 + (size_t)(n >> 5) * 1024
                              + (size_t)(n & 31) * 8;
        *(uint4*)(kbase +   0) = make_uint4(pack_bf2(k[0], k[1]),   pack_bf2(k[2], k[3]),
                                            pack_bf2(k[4], k[5]),   pack_bf2(k[6], k[7]));
        *(uint4*)(kbase + 256) = make_uint4(pack_bf2(k[8], k[9]),   pack_bf2(k[10], k[11]),
                                            pack_bf2(k[12], k[13]), pack_bf2(k[14], k[15]));
        *(uint4*)(kbase + 512) = make_uint4(pack_bf2(klo[0], klo[1]),   pack_bf2(klo[2], klo[3]),
                                            pack_bf2(klo[4], klo[5]),   pack_bf2(klo[6], klo[7]));
        *(uint4*)(kbase + 768) = make_uint4(pack_bf2(klo[8], klo[9]),   pack_bf2(klo[10], klo[11]),
                                            pack_bf2(klo[12], klo[13]), pack_bf2(klo[14], klo[15]));
    } else {
        int gid = (blk - 64) * 256 + threadIdx.x;   // 0..524287
        int c  = gid & 31;
        int h1 = (gid >> 5) & 1;
        int kb = (gid >> 6) & 255;
        int ct = (gid >> 14) & 7;
        int b  = gid >> 17;
        int chan = ct * 32 + c;
        int key  = kb * 16 + h1 * 8;
        const float4* dp = (const float4*)(deep + ((size_t)(b * 256 + chan) * 4096 + key));
        float4 f0 = dp[0], f1 = dp[1];
        ((uint4*)Vb)[gid] = make_uint4(pack_bf2(f0.x, f0.y), pack_bf2(f0.z, f0.w),
                                       pack_bf2(f1.x, f1.y), pack_bf2(f1.z, f1.w));
    }
}

// ---------------- Main fused flash-attention kernel ----------------------
// Grid: 256 blocks x 512 threads (8 waves, 2/SIMD). Block = (b, 64-query
// tile), all 256 chans — the r4 geometry (best measured: V-reuse needs the
// 64-query block; produce-dedup needs unified channels; r7/r8/r11 variants
// all regressed). Wave w: QK^T+softmax for key-slice w of ss+1 AND PV for
// chan-tile w of ss (2 accs). SINGLE CHANGE vs r4 (62.4 us): barriers are
// lgkmcnt-only (LBAR) — no vmcnt(0) drain, so the K(ss+2) prefetch issued
// mid-produce rides across the barrier (T4 counted-wait discipline via the
// compiler's own dependency waits).
__global__ void __launch_bounds__(512, 2) attn_main(
    const uint16_t* __restrict__ Qb, const uint16_t* __restrict__ Kb2,
    const uint16_t* __restrict__ Vb, const float* __restrict__ deep,
    const float* __restrict__ gamma, float* __restrict__ out) {
    const int lane = threadIdx.x & 63;
    const int w    = threadIdx.x >> 6;   // 0..7: key-slice / chan-tile
    const int col  = lane & 31;
    const int h1   = lane >> 5;

    // XCD-locality: one batch per XCD pair (V slice 2 MB < 4 MB L2/XCD).
    const int bid = blockIdx.x;
    const int xcd = bid & 7;
    const int b   = xcd >> 1;
    const int qt  = ((bid >> 3) << 1) + (xcd & 1);   // 0..63
    const int n0q = qt * 64;

    __shared__ uint4 Pl[2][2][16][2][32];  // par, qh, frag, h1', col  = 64 KB
    __shared__ float Ls[2][2][16][32];     // par, qh, w*2+h1, col     =  8 KB

    // Hoisted Q B-frags for both query halves (pre-scaled by LOG2E)
    uint4 ubqh[2], ubql[2];
#pragma unroll
    for (int qh = 0; qh < 2; ++qh) {
        const uint16_t* qrow = Qb + ((size_t)(b * 4096 + n0q + qh * 32 + col)) * 32;
        ubqh[qh] = *(const uint4*)(qrow + h1 * 8);
        ubql[qh] = *(const uint4*)(qrow + 16 + h1 * 8);
    }

    const uint16_t* kbase = Kb2 + (size_t)b * 131072 + (size_t)w * 1024
                                + (size_t)lane * 8;                  // + ss*8192
    const uint16_t* vlane = Vb + (size_t)(b * 8 + w) * 131072
                               + (size_t)h1 * 256 + (size_t)col * 8; // + (ss*16+f)*512

    f32x16 acc0 = {0,0,0,0,0,0,0,0,0,0,0,0,0,0,0,0};
    f32x16 acc1 = {0,0,0,0,0,0,0,0,0,0,0,0,0,0,0,0};
    float l0 = 0.0f, l1 = 0.0f;
    uint4 ukh, ukl;                        // K frags for next produce

    // produce P(s) -> Pl[s&1]; reloads ukh/ukl = K(s+1) after last use.
    auto qk_softmax = [&](int s) {
        const int pr = s & 1;
        bf16x8 akh = __builtin_bit_cast(bf16x8, ukh);
        bf16x8 akl = __builtin_bit_cast(bf16x8, ukl);
#pragma unroll
        for (int qh = 0; qh < 2; ++qh) {
            bf16x8 bh = __builtin_bit_cast(bf16x8, ubqh[qh]);
            bf16x8 bl = __builtin_bit_cast(bf16x8, ubql[qh]);
            f32x16 e = {0,0,0,0,0,0,0,0,0,0,0,0,0,0,0,0};
            e = __builtin_amdgcn_mfma_f32_32x32x16_bf16(akh, bh, e, 0, 0, 0);
            e = __builtin_amdgcn_mfma_f32_32x32x16_bf16(akl, bh, e, 0, 0, 0);
            e = __builtin_amdgcn_mfma_f32_32x32x16_bf16(akh, bl, e, 0, 0, 0);
            if (qh == 1) {                 // K(s+1) reload after last akh/akl use
                const int sn = (s < 15) ? s + 1 : s;
                ukh = *(const uint4*)(kbase + (size_t)sn * 8192);
                ukl = *(const uint4*)(kbase + (size_t)sn * 8192 + 512);
            }
            float p[16];
#pragma unroll
            for (int r = 0; r < 16; ++r) p[r] = exp2f(e[r]);   // Q pre-scaled
            float t0 = (p[0] + p[1]) + (p[2] + p[3]);
            float t1 = (p[4] + p[5]) + (p[6] + p[7]);
            float t2 = (p[8] + p[9]) + (p[10] + p[11]);
            float t3 = (p[12] + p[13]) + (p[14] + p[15]);
            Ls[pr][qh][w * 2 + h1][col] = (t0 + t1) + (t2 + t3);
            uint32_t pk0 = pack_bf2(p[0],  p[1]),  pk1 = pack_bf2(p[2],  p[3]);
            uint32_t pk2 = pack_bf2(p[4],  p[5]),  pk3 = pack_bf2(p[6],  p[7]);
            uint32_t pk4 = pack_bf2(p[8],  p[9]),  pk5 = pack_bf2(p[10], p[11]);
            uint32_t pk6 = pack_bf2(p[12], p[13]), pk7 = pack_bf2(p[14], p[15]);
            ((uint2*)&Pl[pr][qh][2 * w    ][0][col])[h1] = make_uint2(pk0, pk1);
            ((uint2*)&Pl[pr][qh][2 * w    ][1][col])[h1] = make_uint2(pk2, pk3);
            ((uint2*)&Pl[pr][qh][2 * w + 1][0][col])[h1] = make_uint2(pk4, pk5);
            ((uint2*)&Pl[pr][qh][2 * w + 1][1][col])[h1] = make_uint2(pk6, pk7);
        }
    };

// LDS-only barrier: Pl/Ls visibility without draining global loads. Reads
// of Pl/Ls are lgkm-counted too, so the parity double-buffer stays race-free
// (last-read drains before the barrier that precedes the next write).
#define LBAR()                                                      \
    {                                                               \
        asm volatile("s_waitcnt lgkmcnt(0)" ::: "memory");          \
        __builtin_amdgcn_s_barrier();                               \
    }

    // ---- prologue ----
    ukh = *(const uint4*)(kbase);
    ukl = *(const uint4*)(kbase + 512);
    qk_softmax(0);                          // Pl[0]; leaves ukh=K(1)
    LBAR();                                 // barrier 0

    // ---- main loop: one LDS-barrier per superstep ----
#pragma unroll 2
    for (int ss = 0; ss < 16; ++ss) {
        const int par = ss & 1;
        // issue-early V loads for this superstep (consumed after softmax)
        uint4 vr[16];
        const uint16_t* vss = vlane + (size_t)ss * 8192;
#pragma unroll
        for (int f = 0; f < 16; ++f) vr[f] = *(const uint4*)(vss + f * 512);

        if (ss < 15) qk_softmax(ss + 1);    // overlaps with PV below

        __builtin_amdgcn_s_setprio(1);
#pragma unroll
        for (int f = 0; f < 16; ++f) {
            uint4 pb0 = Pl[par][0][f][h1][col];
            uint4 pb1 = Pl[par][1][f][h1][col];
            bf16x8 av = __builtin_bit_cast(bf16x8, vr[f]);
            acc0 = __builtin_amdgcn_mfma_f32_32x32x16_bf16(
                av, __builtin_bit_cast(bf16x8, pb0), acc0, 0, 0, 0);
            acc1 = __builtin_amdgcn_mfma_f32_32x32x16_bf16(
                av, __builtin_bit_cast(bf16x8, pb1), acc1, 0, 0, 0);
        }
        __builtin_amdgcn_s_setprio(0);

#pragma unroll
        for (int j = 0; j < 16; ++j) {
            l0 += Ls[par][0][j][col];
            l1 += Ls[par][1][j][col];
        }
        LBAR();                             // barriers 1..16
    }

    // ---- epilogue: out = gamma * acc/l + deep ----
    const float g   = gamma[0];
    const float gr0 = g / l0;
    const float gr1 = g / l1;
#pragma unroll
    for (int r = 0; r < 16; ++r) {
        const int crow = (r & 3) + 8 * (r >> 2) + 4 * h1;
        const int chan = w * 32 + crow;
        size_t i0 = (size_t)(b * 256 + chan) * 4096 + n0q + col;
        out[i0] = fmaf(gr0, acc0[r], deep[i0]);
        size_t i1 = i0 + 32;
        out[i1] = fmaf(gr1, acc1[r], deep[i1]);
    }
#undef LBAR
}

extern "C" void kernel_launch(void* const* d_in, const int* in_sizes, int n_in,
                              void* d_out, int out_size, void* d_ws, size_t ws_size,
                              hipStream_t stream) {
    const float* deep    = (const float*)d_in[0];
    const float* shallow = (const float*)d_in[1];
    const float* Wq      = (const float*)d_in[2];
    const float* bq      = (const float*)d_in[3];
    const float* Wk      = (const float*)d_in[4];
    const float* bk      = (const float*)d_in[5];
    const float* gamma   = (const float*)d_in[6];
    float* out = (float*)d_out;

    // ws layout: Vb swizzled bf16 (8 MiB) | Qb (1 MiB) | Kb2 (1 MiB)
    uint16_t* Vb  = (uint16_t*)d_ws;
    uint16_t* Qb  = (uint16_t*)((char*)d_ws + (size_t)8 * 1024 * 1024);
    uint16_t* Kb2 = (uint16_t*)((char*)d_ws + (size_t)9 * 1024 * 1024);

    hipLaunchKernelGGL(prepass, dim3(2112), dim3(256), 0, stream,
                       deep, shallow, Wq, bq, Wk, bk, Vb, Qb, Kb2);
    hipLaunchKernelGGL(attn_main, dim3(256), dim3(512), 0, stream,
                       Qb, Kb2, Vb, deep, gamma, out);
}